// Round 8
// baseline (144.529 us; speedup 1.0000x reference)
//
#include <hip/hip_runtime.h>
#include <math.h>

#define N 8192
#define FIN 128
#define FOUT 64
#define ALPHA 0.2f
#define JS 16
#define JLEN (N / JS)          // 512
#define NT (JLEN / 32)         // 16 tiles per block

typedef __attribute__((ext_vector_type(8))) short bf16x8;
typedef __attribute__((ext_vector_type(8))) unsigned short ushort8;
typedef __attribute__((ext_vector_type(4))) float f32x4;

__device__ __forceinline__ unsigned short f2bf(float f) {
    unsigned int u = __float_as_uint(f);
    u += 0x7fff + ((u >> 16) & 1);          // round-to-nearest-even
    return (unsigned short)(u >> 16);
}
__device__ __forceinline__ float elu(float v) { return v > 0.f ? v : expm1f(v); }

__device__ __forceinline__ void gll16(const float* src, float* dst_lds) {
    __builtin_amdgcn_global_load_lds((const __attribute__((address_space(1))) void*)src,
                                     (__attribute__((address_space(3))) void*)dst_lds, 16, 0, 0);
}

// ---------------- Kernel A: h = x @ W, fused s1/s2 epilogue ----------------
__global__ __launch_bounds__(256) void k_h(const float* __restrict__ x,
                                           const float* __restrict__ W,
                                           const float* __restrict__ a,
                                           float* __restrict__ h,
                                           float* __restrict__ s1,
                                           float* __restrict__ s2) {
    __shared__ float Wl[FIN * FOUT];
    int t = threadIdx.x;
    #pragma unroll
    for (int i = 0; i < (FIN * FOUT) / (256 * 4); ++i) {
        int idx = (t + i * 256) * 4;
        *(float4*)&Wl[idx] = *(const float4*)&W[idx];
    }
    __syncthreads();
    int gid = blockIdx.x * 256 + t;
    int row = gid >> 6;
    int c   = gid & 63;
    float acc = 0.f;
    #pragma unroll
    for (int k = 0; k < FIN; k += 4) {
        float4 xv = *(const float4*)&x[row * FIN + k];
        acc = fmaf(xv.x, Wl[(k + 0) * FOUT + c], acc);
        acc = fmaf(xv.y, Wl[(k + 1) * FOUT + c], acc);
        acc = fmaf(xv.z, Wl[(k + 2) * FOUT + c], acc);
        acc = fmaf(xv.w, Wl[(k + 3) * FOUT + c], acc);
    }
    h[gid] = acc;
    float p1 = acc * a[c];
    float p2 = acc * a[64 + c];
    #pragma unroll
    for (int off = 32; off; off >>= 1) {
        p1 += __shfl_xor(p1, off);
        p2 += __shfl_xor(p2, off);
    }
    if (c == 0) { s1[row] = p1; s2[row] = p2; }
}

// ---------------- Kernel C: S2MAX = max(s2) ----------------
__global__ __launch_bounds__(256) void k_max(const float* __restrict__ s2,
                                             float* __restrict__ s2max) {
    __shared__ float red[256];
    float m = -1e30f;
    for (int i = threadIdx.x; i < N; i += 256) m = fmaxf(m, s2[i]);
    red[threadIdx.x] = m;
    __syncthreads();
    #pragma unroll
    for (int s = 128; s; s >>= 1) {
        if (threadIdx.x < s) red[threadIdx.x] = fmaxf(red[threadIdx.x], red[threadIdx.x + s]);
        __syncthreads();
    }
    if (threadIdx.x == 0) *s2max = red[0];
}

// ---------------- Kernel T: hT[c][j] = bf16(h[j][c])  (64 x 8192) ----------------
__global__ __launch_bounds__(256) void k_t(const float* __restrict__ h,
                                           unsigned short* __restrict__ hT) {
    __shared__ float tile[64][65];
    int t = threadIdx.x;
    int j0 = blockIdx.x * 64;
    #pragma unroll
    for (int p = 0; p < 4; ++p) {
        int j = p * 16 + (t >> 4);
        int c4 = (t & 15) * 4;
        float4 v = *(const float4*)&h[(size_t)(j0 + j) * 64 + c4];
        tile[j][c4] = v.x; tile[j][c4 + 1] = v.y; tile[j][c4 + 2] = v.z; tile[j][c4 + 3] = v.w;
    }
    __syncthreads();
    int c = t & 63, seg = t >> 6;
    ushort8 u0, u1;
    #pragma unroll
    for (int k = 0; k < 8; ++k) u0[k] = f2bf(tile[seg * 16 + k][c]);
    #pragma unroll
    for (int k = 0; k < 8; ++k) u1[k] = f2bf(tile[seg * 16 + 8 + k][c]);
    unsigned short* dst = &hT[(size_t)c * N + j0 + seg * 16];
    *(ushort8*)dst = u0;
    *(ushort8*)(dst + 8) = u1;
}

// ---------------- Kernel D: async-pipelined masked softmax + PV via MFMA ----------------
// Wave-private adj staging: global_load_lds (no VGPR cost), 4-deep circular LDS
// buffer, stage 3 tiles ahead, counted s_waitcnt vmcnt(6) -- NO barrier in loop.
// Swizzle: 16B chunk c of row r stored at c^(r&7) (source-side XOR), read with
// same XOR -> <=2-way bank conflict. hT B-frags double-buffered in regs (1 ahead).
__global__ __launch_bounds__(256, 4) void k_attn(const float* __restrict__ adj,
                                                 const unsigned short* __restrict__ hT,
                                                 const float* __restrict__ s1,
                                                 const float* __restrict__ s2,
                                                 const float* __restrict__ s2max,
                                                 float* __restrict__ pacc,
                                                 float* __restrict__ pden) {
    __shared__ float adj_lds[4][4 * 16 * 32];   // [wave][buf*512 + row*32 + chunkpos*4]
    __shared__ float s2_lds[JLEN];

    int wave = threadIdx.x >> 6;
    int lane = threadIdx.x & 63;
    int rb   = blockIdx.x / JS;
    int js   = blockIdx.x % JS;
    int r0w  = rb * 64 + wave * 16;      // this wave's 16 rows
    int jb   = js * JLEN;

    // stage s2 block-slice once (one barrier, prologue only)
    { int t2 = threadIdx.x * 2; *(float2*)&s2_lds[t2] = *(const float2*)&s2[jb + t2]; }
    __syncthreads();

    int row = lane & 15;
    int kg  = lane >> 4;
    int kg8 = kg * 8;
    int r   = r0w + row;

    float s1v = s1[r];
    float S2M = *s2max;
    float pM  = s1v + S2M;
    float Mv  = fmaxf(pM, ALPHA * pM);

    // staging source addresses (lane -> row r8 of 8-row group, swizzled chunk)
    int r8 = lane >> 3;
    int cs = (lane & 7) ^ r8;
    const float* sb0 = adj + (size_t)(r0w + r8) * N + jb + cs * 4;
    const float* sb1 = adj + (size_t)(r0w + 8 + r8) * N + jb + cs * 4;
    float* lb = &adj_lds[wave][0];
    const char* ldsb = (const char*)lb;

    // swizzled read byte-offsets (lane consts)
    int offA = row * 128 + (((2 * kg)     ^ (row & 7)) * 16);
    int offB = row * 128 + (((2 * kg + 1) ^ (row & 7)) * 16);

    // hT per-lane row pointers
    const unsigned short* hb0 = hT + (size_t)(0 * 16 + row) * N + jb + kg8;
    const unsigned short* hb1 = hT + (size_t)(1 * 16 + row) * N + jb + kg8;
    const unsigned short* hb2 = hT + (size_t)(2 * 16 + row) * N + jb + kg8;
    const unsigned short* hb3 = hT + (size_t)(3 * 16 + row) * N + jb + kg8;

    f32x4 acc0 = {0.f, 0.f, 0.f, 0.f};
    f32x4 acc1 = {0.f, 0.f, 0.f, 0.f};
    f32x4 acc2 = {0.f, 0.f, 0.f, 0.f};
    f32x4 acc3 = {0.f, 0.f, 0.f, 0.f};
    float den = 0.f;

    bf16x8 A0, A1, A2, A3, B0, B1, B2, B3;

#define STAGE(buf, ts) do {                      \
        gll16(sb0 + (ts) * 32, lb + (buf) * 512);        \
        gll16(sb1 + (ts) * 32, lb + (buf) * 512 + 256);  \
    } while (0)

    // prologue: stage 0; hT(0); stage 1,2; wait stage0+hT0 (4 newer outstanding)
    STAGE(0, 0);
    A0 = *(const bf16x8*)(hb0);
    A1 = *(const bf16x8*)(hb1);
    A2 = *(const bf16x8*)(hb2);
    A3 = *(const bf16x8*)(hb3);
    STAGE(1, 1);
    STAGE(2, 2);
    asm volatile("s_waitcnt vmcnt(4)" ::: "memory");
    __builtin_amdgcn_sched_barrier(0);

#define BODY(u, CUR0, CUR1, CUR2, CUR3, NXT0, NXT1, NXT2, NXT3) do {          \
        int t  = 4 * p + (u);                                                  \
        int ts = (t + 3) & 15;                                                 \
        int tn = (t + 1) & 15;                                                 \
        STAGE(((u) + 3) & 3, ts);                                              \
        NXT0 = *(const bf16x8*)(hb0 + tn * 32);                                \
        NXT1 = *(const bf16x8*)(hb1 + tn * 32);                                \
        NXT2 = *(const bf16x8*)(hb2 + tn * 32);                                \
        NXT3 = *(const bf16x8*)(hb3 + tn * 32);                                \
        asm volatile("s_waitcnt vmcnt(6)" ::: "memory");                       \
        __builtin_amdgcn_sched_barrier(0);                                     \
        const char* bufp = ldsb + (u) * 2048;                                  \
        float4 aA = *(const float4*)(bufp + offA);                             \
        float4 aB = *(const float4*)(bufp + offB);                             \
        float4 s0 = *(const float4*)&s2_lds[t * 32 + kg8];                     \
        float4 s1q = *(const float4*)&s2_lds[t * 32 + kg8 + 4];                \
        float av[8] = {aA.x, aA.y, aA.z, aA.w, aB.x, aB.y, aB.z, aB.w};        \
        float sv[8] = {s0.x, s0.y, s0.z, s0.w, s1q.x, s1q.y, s1q.z, s1q.w};    \
        union { bf16x8 v; unsigned short u16[8]; } af;                         \
        _Pragma("unroll")                                                      \
        for (int i = 0; i < 8; ++i) {                                          \
            float pre = s1v + sv[i];                                           \
            float e   = fmaxf(pre, ALPHA * pre);                               \
            float w   = av[i] * __expf(e - Mv);                                \
            den += w;                                                          \
            af.u16[i] = f2bf(w);                                               \
        }                                                                      \
        acc0 = __builtin_amdgcn_mfma_f32_16x16x32_bf16(af.v, CUR0, acc0, 0, 0, 0); \
        acc1 = __builtin_amdgcn_mfma_f32_16x16x32_bf16(af.v, CUR1, acc1, 0, 0, 0); \
        acc2 = __builtin_amdgcn_mfma_f32_16x16x32_bf16(af.v, CUR2, acc2, 0, 0, 0); \
        acc3 = __builtin_amdgcn_mfma_f32_16x16x32_bf16(af.v, CUR3, acc3, 0, 0, 0); \
    } while (0)

    for (int p = 0; p < NT / 4; ++p) {
        BODY(0, A0, A1, A2, A3, B0, B1, B2, B3);
        BODY(1, B0, B1, B2, B3, A0, A1, A2, A3);
        BODY(2, A0, A1, A2, A3, B0, B1, B2, B3);
        BODY(3, B0, B1, B2, B3, A0, A1, A2, A3);
    }
#undef BODY
#undef STAGE

    den += __shfl_xor(den, 16);
    den += __shfl_xor(den, 32);

    int r0 = rb * 64 + wave * 16;
    #pragma unroll
    for (int q = 0; q < 4; ++q) {
        int ro = kg * 4 + q;
        size_t ob = ((size_t)js * N + r0 + ro) * 64 + row;
        pacc[ob + 0]  = acc0[q];
        pacc[ob + 16] = acc1[q];
        pacc[ob + 32] = acc2[q];
        pacc[ob + 48] = acc3[q];
    }
    if (lane < 16) pden[(size_t)js * N + r0 + lane] = den;
}

// ---------------- Kernel E: combine partials, div + elu ----------------
__global__ __launch_bounds__(256) void k_combine(const float* __restrict__ pacc,
                                                 const float* __restrict__ pden,
                                                 float* __restrict__ out) {
    int gid = blockIdx.x * 256 + threadIdx.x;
    int row = gid >> 6;
    float a = 0.f, d = 0.f;
    #pragma unroll
    for (int s = 0; s < JS; ++s) {
        a += pacc[((size_t)s * N + row) * 64 + (gid & 63)];
        d += pden[(size_t)s * N + row];
    }
    out[gid] = elu(a / d);
}

// ---------------- launch ----------------
extern "C" void kernel_launch(void* const* d_in, const int* in_sizes, int n_in,
                              void* d_out, int out_size, void* d_ws, size_t ws_size,
                              hipStream_t stream) {
    const float* x   = (const float*)d_in[0];
    const float* adj = (const float*)d_in[1];
    const float* W   = (const float*)d_in[2];
    const float* a   = (const float*)d_in[3];
    float* out = (float*)d_out;

    // ws layout (float units)
    float* ws   = (float*)d_ws;
    float* h    = ws;                                // 524288
    float* s1   = h + (size_t)N * FOUT;              // 8192
    float* s2   = s1 + N;                            // 8192
    float* s2m  = s2 + N;                            // 64
    float* pden = s2m + 64;                          // 16*8192
    unsigned short* hT = (unsigned short*)(pden + 16 * N);   // 262144 float-equiv
    float* pacc = (float*)hT + 262144;               // 16*524288

    k_h<<<dim3((N * FOUT) / 256), dim3(256), 0, stream>>>(x, W, a, h, s1, s2);
    k_max<<<dim3(1), dim3(256), 0, stream>>>(s2, s2m);
    k_t<<<dim3(N / 64), dim3(256), 0, stream>>>(h, hT);

    k_attn<<<dim3(128 * JS), dim3(256), 0, stream>>>(adj, hT, s1, s2, s2m, pacc, pden);
    k_combine<<<dim3((N * FOUT) / 256), dim3(256), 0, stream>>>(pacc, pden, out);
}